// Round 1
// baseline (1686.323 us; speedup 1.0000x reference)
//
#include <hip/hip_runtime.h>
#include <hip/hip_bf16.h>

#define N_ROWS 100000
#define IN_C   128
#define OUT_C  64
#define S_SC   3
#define NNZ    1600000
#define NMAT   7
#define NCOL   8      // color-privatized counter copies (~XCDs)

#define SEG       512
#define BLKS_SCAN 196   // 196*512 = 100352 >= 100000

struct RowPtrs { const int* p[NMAT]; };

__device__ __forceinline__ float bf2f(__hip_bfloat16 x) { return __bfloat162float(x); }

// ---------------------------------------------------------------------------
// 1) Colored histogram, all 7 matrices: counts8[(m*NCOL+color)][r] += 1
// ---------------------------------------------------------------------------
__global__ __launch_bounds__(256)
void hist_all(RowPtrs P, int* __restrict__ counts8)
{
    const int m = blockIdx.y;
    const int e = blockIdx.x * 256 + threadIdx.x;
    const int color = blockIdx.x & (NCOL - 1);
    if (e < NNZ)
        atomicAdd(&counts8[((size_t)m * NCOL + color) * N_ROWS + P.p[m][e]], 1);
}

// ---------------------------------------------------------------------------
// 2a) Per-512-row block scan of totals (sum over colors) + block sums
// ---------------------------------------------------------------------------
__global__ __launch_bounds__(256)
void scan_l1(const int* __restrict__ counts8, int* __restrict__ row_start,
             int* __restrict__ bsum)
{
    __shared__ int buf[2][SEG];
    const int m   = blockIdx.y;
    const int blk = blockIdx.x;
    const int t   = threadIdx.x;
    const int* cnt = counts8 + (size_t)m * NCOL * N_ROWS;

    for (int k = t; k < SEG; k += 256) {
        const int g = blk * SEG + k;
        int tot = 0;
        if (g < N_ROWS)
            for (int c = 0; c < NCOL; ++c) tot += cnt[c * N_ROWS + g];
        buf[0][k] = tot;
    }
    __syncthreads();

    int src = 0;
    for (int off = 1; off < SEG; off <<= 1) {
        for (int k = t; k < SEG; k += 256) {
            int v = buf[src][k];
            if (k >= off) v += buf[src][k - off];
            buf[1 - src][k] = v;
        }
        src ^= 1;
        __syncthreads();
    }
    for (int k = t; k < SEG; k += 256) {
        const int g = blk * SEG + k;
        if (g < N_ROWS)
            row_start[m * N_ROWS + g] = (k == 0) ? 0 : buf[src][k - 1];
    }
    if (t == 0) bsum[m * 256 + blk] = buf[src][SEG - 1];
}

// ---------------------------------------------------------------------------
// 2b) Exclusive scan of block sums; one block per matrix
// ---------------------------------------------------------------------------
__global__ __launch_bounds__(256)
void scan_l2(int* __restrict__ bsum)
{
    __shared__ int buf[2][256];
    const int t = threadIdx.x;
    int* b = bsum + blockIdx.x * 256;
    buf[0][t] = (t < BLKS_SCAN) ? b[t] : 0;
    __syncthreads();
    int src = 0;
    for (int off = 1; off < 256; off <<= 1) {
        int v = buf[src][t];
        if (t >= off) v += buf[src][t - off];
        buf[1 - src][t] = v;
        src ^= 1;
        __syncthreads();
    }
    if (t < BLKS_SCAN) b[t] = (t == 0) ? 0 : buf[src][t - 1];
}

// ---------------------------------------------------------------------------
// 2c) Finalize: absolute row_start/row_end; counts8 -> per-color cursors
// ---------------------------------------------------------------------------
__global__ __launch_bounds__(256)
void finalize(const int* __restrict__ bsum, int* __restrict__ row_start,
              int* __restrict__ row_end, int* __restrict__ counts8)
{
    const int i = blockIdx.x * 256 + threadIdx.x;
    if (i >= NMAT * N_ROWS) return;
    const int m = i / N_ROWS;
    const int r = i - m * N_ROWS;
    int* cnt = counts8 + (size_t)m * NCOL * N_ROWS;
    const int base = row_start[i] + bsum[m * 256 + r / SEG];
    row_start[i] = base;
    int running = base;
    for (int c = 0; c < NCOL; ++c) {
        const int v = cnt[c * N_ROWS + r];
        cnt[c * N_ROWS + r] = running;      // becomes cursor
        running += v;
    }
    row_end[i] = running;
}

// ---------------------------------------------------------------------------
// 3) Colored fill: one packed 8B (col,val) store per nnz
// ---------------------------------------------------------------------------
__global__ __launch_bounds__(256)
void fill8(const int* __restrict__ rows, const int* __restrict__ cols,
           const float* __restrict__ vals, int* __restrict__ cur8,
           uint2* __restrict__ scv)
{
    const int e = blockIdx.x * 256 + threadIdx.x;
    const int color = blockIdx.x & (NCOL - 1);
    if (e < NNZ) {
        const int pos = atomicAdd(&cur8[color * N_ROWS + rows[e]], 1);
        scv[pos] = make_uint2((unsigned)cols[e], __float_as_uint(vals[e]));
    }
}

// ---------------------------------------------------------------------------
// 4a) Gather-SPMM vs LDS W (fp32): filtered[r] = bf16(sum v * W[c])
// ---------------------------------------------------------------------------
__global__ __launch_bounds__(256)
void gather_W(const int* __restrict__ start, const int* __restrict__ end,
              const uint2* __restrict__ scv, const float* __restrict__ W,
              __hip_bfloat16* __restrict__ dst)
{
    __shared__ float Wl[IN_C * OUT_C];
    for (int i = threadIdx.x; i < IN_C * OUT_C; i += blockDim.x) Wl[i] = W[i];
    __syncthreads();

    const int lane = threadIdx.x & 63;
    const int wave = blockIdx.x * 4 + (threadIdx.x >> 6);
    const int nw   = gridDim.x * 4;

    for (int r = wave; r < N_ROWS; r += nw) {
        const int s = start[r], t = end[r];
        float a0 = 0.f, a1 = 0.f, a2 = 0.f, a3 = 0.f;
        int j = s;
        for (; j + 3 < t; j += 4) {
            const uint2 p0 = scv[j],     p1 = scv[j + 1];
            const uint2 p2 = scv[j + 2], p3 = scv[j + 3];
            a0 += __uint_as_float(p0.y) * Wl[p0.x * OUT_C + lane];
            a1 += __uint_as_float(p1.y) * Wl[p1.x * OUT_C + lane];
            a2 += __uint_as_float(p2.y) * Wl[p2.x * OUT_C + lane];
            a3 += __uint_as_float(p3.y) * Wl[p3.x * OUT_C + lane];
        }
        for (; j < t; ++j) {
            const uint2 p = scv[j];
            a0 += __uint_as_float(p.y) * Wl[p.x * OUT_C + lane];
        }
        dst[r * OUT_C + lane] = __float2bfloat16((a0 + a1) + (a2 + a3));
    }
}

// ---------------------------------------------------------------------------
// 4b) Gather-SPMM from bf16 src (wave-uniform pair loads, x4 unroll).
// MODE 1: dst[r] = bf16(theta[r] * sum v*src[c])
// MODE 2: out[(r*3+scale)] = relu(sum v*src[c])   (fp32)
// ---------------------------------------------------------------------------
template <int MODE>
__global__ __launch_bounds__(256)
void gather_mat(const int* __restrict__ start, const int* __restrict__ end,
                const uint2* __restrict__ scv,
                const __hip_bfloat16* __restrict__ src,
                const float* __restrict__ theta,
                __hip_bfloat16* __restrict__ dstb,
                float* __restrict__ dstf, int scale)
{
    const int lane = threadIdx.x & 63;
    const int wave = blockIdx.x * 4 + (threadIdx.x >> 6);
    const int nw   = gridDim.x * 4;

    for (int r = wave; r < N_ROWS; r += nw) {
        const int s = start[r], t = end[r];
        float a0 = 0.f, a1 = 0.f, a2 = 0.f, a3 = 0.f;
        int j = s;
        for (; j + 3 < t; j += 4) {
            const uint2 p0 = scv[j],     p1 = scv[j + 1];
            const uint2 p2 = scv[j + 2], p3 = scv[j + 3];
            const float w0 = bf2f(src[p0.x * OUT_C + lane]);
            const float w1 = bf2f(src[p1.x * OUT_C + lane]);
            const float w2 = bf2f(src[p2.x * OUT_C + lane]);
            const float w3 = bf2f(src[p3.x * OUT_C + lane]);
            a0 += __uint_as_float(p0.y) * w0;
            a1 += __uint_as_float(p1.y) * w1;
            a2 += __uint_as_float(p2.y) * w2;
            a3 += __uint_as_float(p3.y) * w3;
        }
        for (; j < t; ++j) {
            const uint2 p = scv[j];
            a0 += __uint_as_float(p.y) * bf2f(src[p.x * OUT_C + lane]);
        }
        const float acc = (a0 + a1) + (a2 + a3);
        if (MODE == 1) {
            dstb[r * OUT_C + lane] = __float2bfloat16(theta[r] * acc);
        } else {
            dstf[(r * S_SC + scale) * OUT_C + lane] = acc > 0.0f ? acc : 0.0f;
        }
    }
}

extern "C" void kernel_launch(void* const* d_in, const int* in_sizes, int n_in,
                              void* d_out, int out_size, void* d_ws, size_t ws_size,
                              hipStream_t stream)
{
    const int*   phi_idx  = (const int*)d_in[0];
    const float* phi_val  = (const float*)d_in[1];
    const int*   pinv_idx = (const int*)d_in[2];
    const float* pinv_val = (const float*)d_in[3];
    const int*   fidx     = (const int*)d_in[4];
    const float* fval     = (const float*)d_in[5];
    const float* W        = (const float*)d_in[6];
    const float* theta    = (const float*)d_in[7];
    float*       out      = (float*)d_out;          // (N,S,64) fp32

    // ---- workspace (≈66.3 MB; 76.8 MB proven) ----
    __hip_bfloat16* filtered = (__hip_bfloat16*)d_ws;                  // 12.8 MB
    __hip_bfloat16* z        = filtered + (size_t)N_ROWS * OUT_C;      // 12.8 MB
    int*   counts8   = (int*)(z + (size_t)N_ROWS * OUT_C);             // 22.4 MB
    int*   row_start = counts8 + (size_t)NMAT * NCOL * N_ROWS;         // 2.8 MB
    int*   row_end   = row_start + NMAT * N_ROWS;                      // 2.8 MB
    int*   bsum      = row_end + NMAT * N_ROWS;                        // 7 KB
    uint2* scv       = (uint2*)(bsum + NMAT * 256);                    // 12.8 MB

    // matrix order: 0=F, per scale i: 1+2i=PhiInv_i, 2+2i=Phi_i
    RowPtrs P;
    P.p[0] = fidx;
    for (int i = 0; i < S_SC; ++i) {
        P.p[1 + 2 * i] = pinv_idx + (size_t)(2 * i) * NNZ;
        P.p[2 + 2 * i] = phi_idx  + (size_t)(2 * i) * NNZ;
    }

    // ---- batched CSR metadata for all 7 matrices ----
    hipMemsetAsync(counts8, 0, (size_t)NMAT * NCOL * N_ROWS * sizeof(int), stream);
    hist_all<<<dim3(NNZ / 256, NMAT), 256, 0, stream>>>(P, counts8);
    scan_l1<<<dim3(BLKS_SCAN, NMAT), 256, 0, stream>>>(counts8, row_start, bsum);
    scan_l2<<<NMAT, 256, 0, stream>>>(bsum);
    finalize<<<(NMAT * N_ROWS + 255) / 256, 256, 0, stream>>>(bsum, row_start,
                                                              row_end, counts8);

    // ---- m=0: filtered = bf16(F @ W) ----
    fill8<<<NNZ / 256, 256, 0, stream>>>(fidx, fidx + NNZ, fval, counts8, scv);
    gather_W<<<2048, 256, 0, stream>>>(row_start, row_end, scv, W, filtered);

    for (int i = 0; i < S_SC; ++i) {
        const int m1 = 1 + 2 * i, m2 = 2 + 2 * i;
        const int*   zc = pinv_idx + (size_t)(2 * i + 1) * NNZ;
        const float* zv = pinv_val + (size_t)i * NNZ;
        const int*   oc = phi_idx  + (size_t)(2 * i + 1) * NNZ;
        const float* ov = phi_val  + (size_t)i * NNZ;

        // z = bf16(theta ⊙ (PhiInv_i @ filtered))
        fill8<<<NNZ / 256, 256, 0, stream>>>(P.p[m1], zc, zv,
                                             counts8 + (size_t)m1 * NCOL * N_ROWS, scv);
        gather_mat<1><<<4096, 256, 0, stream>>>(row_start + m1 * N_ROWS,
                                                row_end + m1 * N_ROWS, scv,
                                                filtered, theta, z, nullptr, 0);

        // out[:, i, :] = relu(Phi_i @ z)
        fill8<<<NNZ / 256, 256, 0, stream>>>(P.p[m2], oc, ov,
                                             counts8 + (size_t)m2 * NCOL * N_ROWS, scv);
        gather_mat<2><<<4096, 256, 0, stream>>>(row_start + m2 * N_ROWS,
                                                row_end + m2 * N_ROWS, scv,
                                                z, nullptr, nullptr, out, i);
    }
}

// Round 2
// 1372.346 us; speedup vs baseline: 1.2288x; 1.2288x over previous
//
#include <hip/hip_runtime.h>
#include <hip/hip_bf16.h>

#define N_ROWS 100000
#define IN_C   128
#define OUT_C  64
#define S_SC   3
#define NNZ    1600000
#define NMAT   7
#define NCOL   8      // edge-chunk "colors": c = (e>>8)&7, matches fill8 blockIdx&7

#define SEG       512
#define BLKS_SCAN 196   // 196*512 = 100352 >= 100000

#define NSEG   (NNZ / 256)   // 6250 256-edge segments
#define RPB    25000         // rows per histogram bin
#define NBIN_H 4             // 4*25000 = 100000 exact

struct RowPtrs { const int* p[NMAT]; };

__device__ __forceinline__ float bf2f(__hip_bfloat16 x) { return __bfloat162float(x); }

// ---------------------------------------------------------------------------
// 1) Binned histogram, zero global atomics.
//    Block = (matrix m, chunk c, row-bin). Streams chunk-c's edges (the 256-edge
//    segments with seg%8==c, identical to fill8's blockIdx&7 coloring), counts
//    rows in [bin0, bin0+RPB) in packed-u16 LDS, stores exclusive slice.
// ---------------------------------------------------------------------------
__global__ __launch_bounds__(512)
void hist_binned(RowPtrs P, int* __restrict__ counts8)
{
    __shared__ unsigned cnt[RPB / 2];          // 25000 u16 packed in 12500 u32 (50 KB)
    const int m    = blockIdx.y;
    const int c    = blockIdx.x & 7;           // chunk == color
    const int bin0 = (blockIdx.x >> 3) * RPB;
    const int t    = threadIdx.x;

    for (int i = t; i < RPB / 2; i += 512) cnt[i] = 0;
    __syncthreads();

    const int* rows = P.p[m];
    const int wv = t >> 6;      // 0..7  (wave id)
    const int ln = t & 63;      // lane

    // segments of this color: sg = c, c+8, c+16, ...  Each wave takes one seg
    // (64 lanes x int4 = 256 ints) per iteration; 8 waves -> stride 64.
    for (int sg = c + 8 * wv; sg < NSEG; sg += 64) {
        const int4 v = ((const int4*)rows)[sg * 64 + ln];
        unsigned i0 = (unsigned)(v.x - bin0);
        unsigned i1 = (unsigned)(v.y - bin0);
        unsigned i2 = (unsigned)(v.z - bin0);
        unsigned i3 = (unsigned)(v.w - bin0);
        if (i0 < RPB) atomicAdd(&cnt[i0 >> 1], 1u << ((i0 & 1) * 16));
        if (i1 < RPB) atomicAdd(&cnt[i1 >> 1], 1u << ((i1 & 1) * 16));
        if (i2 < RPB) atomicAdd(&cnt[i2 >> 1], 1u << ((i2 & 1) * 16));
        if (i3 < RPB) atomicAdd(&cnt[i3 >> 1], 1u << ((i3 & 1) * 16));
    }
    __syncthreads();

    // exclusive owner of counts8[m][c][bin0 .. bin0+RPB): plain stores
    int* dst = counts8 + ((size_t)m * NCOL + c) * N_ROWS + bin0;
    for (int i = t; i < RPB / 2; i += 512) {
        const unsigned w = cnt[i];
        ((int2*)dst)[i] = make_int2((int)(w & 0xffffu), (int)(w >> 16));
    }
}

// ---------------------------------------------------------------------------
// 2a) Per-512-row block scan of totals (sum over colors) + block sums
// ---------------------------------------------------------------------------
__global__ __launch_bounds__(256)
void scan_l1(const int* __restrict__ counts8, int* __restrict__ row_start,
             int* __restrict__ bsum)
{
    __shared__ int buf[2][SEG];
    const int m   = blockIdx.y;
    const int blk = blockIdx.x;
    const int t   = threadIdx.x;
    const int* cnt = counts8 + (size_t)m * NCOL * N_ROWS;

    for (int k = t; k < SEG; k += 256) {
        const int g = blk * SEG + k;
        int tot = 0;
        if (g < N_ROWS)
            for (int c = 0; c < NCOL; ++c) tot += cnt[c * N_ROWS + g];
        buf[0][k] = tot;
    }
    __syncthreads();

    int src = 0;
    for (int off = 1; off < SEG; off <<= 1) {
        for (int k = t; k < SEG; k += 256) {
            int v = buf[src][k];
            if (k >= off) v += buf[src][k - off];
            buf[1 - src][k] = v;
        }
        src ^= 1;
        __syncthreads();
    }
    for (int k = t; k < SEG; k += 256) {
        const int g = blk * SEG + k;
        if (g < N_ROWS)
            row_start[m * N_ROWS + g] = (k == 0) ? 0 : buf[src][k - 1];
    }
    if (t == 0) bsum[m * 256 + blk] = buf[src][SEG - 1];
}

// ---------------------------------------------------------------------------
// 2b) Exclusive scan of block sums; one block per matrix
// ---------------------------------------------------------------------------
__global__ __launch_bounds__(256)
void scan_l2(int* __restrict__ bsum)
{
    __shared__ int buf[2][256];
    const int t = threadIdx.x;
    int* b = bsum + blockIdx.x * 256;
    buf[0][t] = (t < BLKS_SCAN) ? b[t] : 0;
    __syncthreads();
    int src = 0;
    for (int off = 1; off < 256; off <<= 1) {
        int v = buf[src][t];
        if (t >= off) v += buf[src][t - off];
        buf[1 - src][t] = v;
        src ^= 1;
        __syncthreads();
    }
    if (t < BLKS_SCAN) b[t] = (t == 0) ? 0 : buf[src][t - 1];
}

// ---------------------------------------------------------------------------
// 2c) Finalize: absolute row_start/row_end; counts8 -> per-color cursors
// ---------------------------------------------------------------------------
__global__ __launch_bounds__(256)
void finalize(const int* __restrict__ bsum, int* __restrict__ row_start,
              int* __restrict__ row_end, int* __restrict__ counts8)
{
    const int i = blockIdx.x * 256 + threadIdx.x;
    if (i >= NMAT * N_ROWS) return;
    const int m = i / N_ROWS;
    const int r = i - m * N_ROWS;
    int* cnt = counts8 + (size_t)m * NCOL * N_ROWS;
    const int base = row_start[i] + bsum[m * 256 + r / SEG];
    row_start[i] = base;
    int running = base;
    for (int c = 0; c < NCOL; ++c) {
        const int v = cnt[c * N_ROWS + r];
        cnt[c * N_ROWS + r] = running;      // becomes cursor
        running += v;
    }
    row_end[i] = running;
}

// ---------------------------------------------------------------------------
// 3) Colored fill: one packed 8B (col,val) store per nnz
// ---------------------------------------------------------------------------
__global__ __launch_bounds__(256)
void fill8(const int* __restrict__ rows, const int* __restrict__ cols,
           const float* __restrict__ vals, int* __restrict__ cur8,
           uint2* __restrict__ scv)
{
    const int e = blockIdx.x * 256 + threadIdx.x;
    const int color = blockIdx.x & (NCOL - 1);
    if (e < NNZ) {
        const int pos = atomicAdd(&cur8[color * N_ROWS + rows[e]], 1);
        scv[pos] = make_uint2((unsigned)cols[e], __float_as_uint(vals[e]));
    }
}

// ---------------------------------------------------------------------------
// 4a) Gather-SPMM vs LDS W (fp32): filtered[r] = bf16(sum v * W[c])
// ---------------------------------------------------------------------------
__global__ __launch_bounds__(256)
void gather_W(const int* __restrict__ start, const int* __restrict__ end,
              const uint2* __restrict__ scv, const float* __restrict__ W,
              __hip_bfloat16* __restrict__ dst)
{
    __shared__ float Wl[IN_C * OUT_C];
    for (int i = threadIdx.x; i < IN_C * OUT_C; i += blockDim.x) Wl[i] = W[i];
    __syncthreads();

    const int lane = threadIdx.x & 63;
    const int wave = blockIdx.x * 4 + (threadIdx.x >> 6);
    const int nw   = gridDim.x * 4;

    for (int r = wave; r < N_ROWS; r += nw) {
        const int s = start[r], t = end[r];
        float a0 = 0.f, a1 = 0.f, a2 = 0.f, a3 = 0.f;
        int j = s;
        for (; j + 3 < t; j += 4) {
            const uint2 p0 = scv[j],     p1 = scv[j + 1];
            const uint2 p2 = scv[j + 2], p3 = scv[j + 3];
            a0 += __uint_as_float(p0.y) * Wl[p0.x * OUT_C + lane];
            a1 += __uint_as_float(p1.y) * Wl[p1.x * OUT_C + lane];
            a2 += __uint_as_float(p2.y) * Wl[p2.x * OUT_C + lane];
            a3 += __uint_as_float(p3.y) * Wl[p3.x * OUT_C + lane];
        }
        for (; j < t; ++j) {
            const uint2 p = scv[j];
            a0 += __uint_as_float(p.y) * Wl[p.x * OUT_C + lane];
        }
        dst[r * OUT_C + lane] = __float2bfloat16((a0 + a1) + (a2 + a3));
    }
}

// ---------------------------------------------------------------------------
// 4b) Gather-SPMM from bf16 src (wave-uniform pair loads, x4 unroll).
// MODE 1: dst[r] = bf16(theta[r] * sum v*src[c])
// MODE 2: out[(r*3+scale)] = relu(sum v*src[c])   (fp32)
// ---------------------------------------------------------------------------
template <int MODE>
__global__ __launch_bounds__(256)
void gather_mat(const int* __restrict__ start, const int* __restrict__ end,
                const uint2* __restrict__ scv,
                const __hip_bfloat16* __restrict__ src,
                const float* __restrict__ theta,
                __hip_bfloat16* __restrict__ dstb,
                float* __restrict__ dstf, int scale)
{
    const int lane = threadIdx.x & 63;
    const int wave = blockIdx.x * 4 + (threadIdx.x >> 6);
    const int nw   = gridDim.x * 4;

    for (int r = wave; r < N_ROWS; r += nw) {
        const int s = start[r], t = end[r];
        float a0 = 0.f, a1 = 0.f, a2 = 0.f, a3 = 0.f;
        int j = s;
        for (; j + 3 < t; j += 4) {
            const uint2 p0 = scv[j],     p1 = scv[j + 1];
            const uint2 p2 = scv[j + 2], p3 = scv[j + 3];
            const float w0 = bf2f(src[p0.x * OUT_C + lane]);
            const float w1 = bf2f(src[p1.x * OUT_C + lane]);
            const float w2 = bf2f(src[p2.x * OUT_C + lane]);
            const float w3 = bf2f(src[p3.x * OUT_C + lane]);
            a0 += __uint_as_float(p0.y) * w0;
            a1 += __uint_as_float(p1.y) * w1;
            a2 += __uint_as_float(p2.y) * w2;
            a3 += __uint_as_float(p3.y) * w3;
        }
        for (; j < t; ++j) {
            const uint2 p = scv[j];
            a0 += __uint_as_float(p.y) * bf2f(src[p.x * OUT_C + lane]);
        }
        const float acc = (a0 + a1) + (a2 + a3);
        if (MODE == 1) {
            dstb[r * OUT_C + lane] = __float2bfloat16(theta[r] * acc);
        } else {
            dstf[(r * S_SC + scale) * OUT_C + lane] = acc > 0.0f ? acc : 0.0f;
        }
    }
}

extern "C" void kernel_launch(void* const* d_in, const int* in_sizes, int n_in,
                              void* d_out, int out_size, void* d_ws, size_t ws_size,
                              hipStream_t stream)
{
    const int*   phi_idx  = (const int*)d_in[0];
    const float* phi_val  = (const float*)d_in[1];
    const int*   pinv_idx = (const int*)d_in[2];
    const float* pinv_val = (const float*)d_in[3];
    const int*   fidx     = (const int*)d_in[4];
    const float* fval     = (const float*)d_in[5];
    const float* W        = (const float*)d_in[6];
    const float* theta    = (const float*)d_in[7];
    float*       out      = (float*)d_out;          // (N,S,64) fp32

    // ---- workspace (≈66.3 MB; 76.8 MB proven) ----
    __hip_bfloat16* filtered = (__hip_bfloat16*)d_ws;                  // 12.8 MB
    __hip_bfloat16* z        = filtered + (size_t)N_ROWS * OUT_C;      // 12.8 MB
    int*   counts8   = (int*)(z + (size_t)N_ROWS * OUT_C);             // 22.4 MB
    int*   row_start = counts8 + (size_t)NMAT * NCOL * N_ROWS;         // 2.8 MB
    int*   row_end   = row_start + NMAT * N_ROWS;                      // 2.8 MB
    int*   bsum      = row_end + NMAT * N_ROWS;                        // 7 KB
    uint2* scv       = (uint2*)(bsum + NMAT * 256);                    // 12.8 MB

    // matrix order: 0=F, per scale i: 1+2i=PhiInv_i, 2+2i=Phi_i
    RowPtrs P;
    P.p[0] = fidx;
    for (int i = 0; i < S_SC; ++i) {
        P.p[1 + 2 * i] = pinv_idx + (size_t)(2 * i) * NNZ;
        P.p[2 + 2 * i] = phi_idx  + (size_t)(2 * i) * NNZ;
    }

    // ---- batched CSR metadata for all 7 matrices (no memset needed:
    //      hist_binned overwrites every counts8 entry) ----
    hist_binned<<<dim3(NCOL * NBIN_H, NMAT), 512, 0, stream>>>(P, counts8);
    scan_l1<<<dim3(BLKS_SCAN, NMAT), 256, 0, stream>>>(counts8, row_start, bsum);
    scan_l2<<<NMAT, 256, 0, stream>>>(bsum);
    finalize<<<(NMAT * N_ROWS + 255) / 256, 256, 0, stream>>>(bsum, row_start,
                                                              row_end, counts8);

    // ---- m=0: filtered = bf16(F @ W) ----
    fill8<<<NNZ / 256, 256, 0, stream>>>(fidx, fidx + NNZ, fval, counts8, scv);
    gather_W<<<2048, 256, 0, stream>>>(row_start, row_end, scv, W, filtered);

    for (int i = 0; i < S_SC; ++i) {
        const int m1 = 1 + 2 * i, m2 = 2 + 2 * i;
        const int*   zc = pinv_idx + (size_t)(2 * i + 1) * NNZ;
        const float* zv = pinv_val + (size_t)i * NNZ;
        const int*   oc = phi_idx  + (size_t)(2 * i + 1) * NNZ;
        const float* ov = phi_val  + (size_t)i * NNZ;

        // z = bf16(theta ⊙ (PhiInv_i @ filtered))
        fill8<<<NNZ / 256, 256, 0, stream>>>(P.p[m1], zc, zv,
                                             counts8 + (size_t)m1 * NCOL * N_ROWS, scv);
        gather_mat<1><<<4096, 256, 0, stream>>>(row_start + m1 * N_ROWS,
                                                row_end + m1 * N_ROWS, scv,
                                                filtered, theta, z, nullptr, 0);

        // out[:, i, :] = relu(Phi_i @ z)
        fill8<<<NNZ / 256, 256, 0, stream>>>(P.p[m2], oc, ov,
                                             counts8 + (size_t)m2 * NCOL * N_ROWS, scv);
        gather_mat<2><<<4096, 256, 0, stream>>>(row_start + m2 * N_ROWS,
                                                row_end + m2 * N_ROWS, scv,
                                                z, nullptr, nullptr, out, i);
    }
}

// Round 3
// 1108.984 us; speedup vs baseline: 1.5206x; 1.2375x over previous
//
#include <hip/hip_runtime.h>
#include <hip/hip_bf16.h>

#define N_ROWS 100000
#define IN_C   128
#define OUT_C  64
#define S_SC   3
#define NNZ    1600000
#define NMAT   7
#define NCOL   8      // hist chunk-copies (parallelism only)

#define SEG       512
#define BLKS_SCAN 196   // 196*512 = 100352 >= 100000

#define NSEG   (NNZ / 256)   // 6250 256-edge segments
#define RPB    25000         // rows per histogram bin
#define NBIN_H 4             // 4*25000 = 100000 exact

#define RPB_F  1024                          // rows per fill bucket (2^10)
#define NBKT   98                            // ceil(100000/1024)
#define EPB_A  2048                          // edges per pass-A block
#define BLKS_A ((NNZ + EPB_A - 1) / EPB_A)   // 782
#define RS_STR (N_ROWS + 1)                  // row_start stride (CSR-style)

struct RowPtrs { const int* p[NMAT]; };

__device__ __forceinline__ float bf2f(__hip_bfloat16 x) { return __bfloat162float(x); }

// ---------------------------------------------------------------------------
// 1) Binned histogram, zero global atomics (unchanged from prev round).
// ---------------------------------------------------------------------------
__global__ __launch_bounds__(512)
void hist_binned(RowPtrs P, int* __restrict__ counts8)
{
    __shared__ unsigned cnt[RPB / 2];          // 25000 u16 packed (50 KB)
    const int m    = blockIdx.y;
    const int c    = blockIdx.x & 7;
    const int bin0 = (blockIdx.x >> 3) * RPB;
    const int t    = threadIdx.x;

    for (int i = t; i < RPB / 2; i += 512) cnt[i] = 0;
    __syncthreads();

    const int* rows = P.p[m];
    const int wv = t >> 6;
    const int ln = t & 63;

    for (int sg = c + 8 * wv; sg < NSEG; sg += 64) {
        const int4 v = ((const int4*)rows)[sg * 64 + ln];
        unsigned i0 = (unsigned)(v.x - bin0);
        unsigned i1 = (unsigned)(v.y - bin0);
        unsigned i2 = (unsigned)(v.z - bin0);
        unsigned i3 = (unsigned)(v.w - bin0);
        if (i0 < RPB) atomicAdd(&cnt[i0 >> 1], 1u << ((i0 & 1) * 16));
        if (i1 < RPB) atomicAdd(&cnt[i1 >> 1], 1u << ((i1 & 1) * 16));
        if (i2 < RPB) atomicAdd(&cnt[i2 >> 1], 1u << ((i2 & 1) * 16));
        if (i3 < RPB) atomicAdd(&cnt[i3 >> 1], 1u << ((i3 & 1) * 16));
    }
    __syncthreads();

    int* dst = counts8 + ((size_t)m * NCOL + c) * N_ROWS + bin0;
    for (int i = t; i < RPB / 2; i += 512) {
        const unsigned w = cnt[i];
        ((int2*)dst)[i] = make_int2((int)(w & 0xffffu), (int)(w >> 16));
    }
}

// ---------------------------------------------------------------------------
// 2a) Per-512-row block scan of totals (sum over chunk-copies) + block sums
// ---------------------------------------------------------------------------
__global__ __launch_bounds__(256)
void scan_l1(const int* __restrict__ counts8, int* __restrict__ rs,
             int* __restrict__ bsum)
{
    __shared__ int buf[2][SEG];
    const int m   = blockIdx.y;
    const int blk = blockIdx.x;
    const int t   = threadIdx.x;
    const int* cnt = counts8 + (size_t)m * NCOL * N_ROWS;

    for (int k = t; k < SEG; k += 256) {
        const int g = blk * SEG + k;
        int tot = 0;
        if (g < N_ROWS)
            for (int c = 0; c < NCOL; ++c) tot += cnt[c * N_ROWS + g];
        buf[0][k] = tot;
    }
    __syncthreads();

    int src = 0;
    for (int off = 1; off < SEG; off <<= 1) {
        for (int k = t; k < SEG; k += 256) {
            int v = buf[src][k];
            if (k >= off) v += buf[src][k - off];
            buf[1 - src][k] = v;
        }
        src ^= 1;
        __syncthreads();
    }
    for (int k = t; k < SEG; k += 256) {
        const int g = blk * SEG + k;
        if (g < N_ROWS)
            rs[(size_t)m * RS_STR + g] = (k == 0) ? 0 : buf[src][k - 1];
    }
    if (t == 0) bsum[m * 256 + blk] = buf[src][SEG - 1];
}

// ---------------------------------------------------------------------------
// 2b) Exclusive scan of block sums; one block per matrix
// ---------------------------------------------------------------------------
__global__ __launch_bounds__(256)
void scan_l2(int* __restrict__ bsum)
{
    __shared__ int buf[2][256];
    const int t = threadIdx.x;
    int* b = bsum + blockIdx.x * 256;
    buf[0][t] = (t < BLKS_SCAN) ? b[t] : 0;
    __syncthreads();
    int src = 0;
    for (int off = 1; off < 256; off <<= 1) {
        int v = buf[src][t];
        if (t >= off) v += buf[src][t - off];
        buf[1 - src][t] = v;
        src ^= 1;
        __syncthreads();
    }
    if (t < BLKS_SCAN) b[t] = (t == 0) ? 0 : buf[src][t - 1];
}

// ---------------------------------------------------------------------------
// 2c) Finalize: absolute row starts; bucket cursors; terminal NNZ sentinel
// ---------------------------------------------------------------------------
__global__ __launch_bounds__(256)
void finalize(const int* __restrict__ bsum, int* __restrict__ rs,
              int* __restrict__ bucket_cur)
{
    const int i = blockIdx.x * 256 + threadIdx.x;
    if (i >= NMAT * N_ROWS) return;
    const int m = i / N_ROWS;
    const int r = i - m * N_ROWS;
    const size_t ri = (size_t)m * RS_STR + r;
    const int base = rs[ri] + bsum[m * 256 + r / SEG];
    rs[ri] = base;
    if ((r & (RPB_F - 1)) == 0) bucket_cur[m * NBKT + (r >> 10)] = base;
    if (r == 0) rs[(size_t)m * RS_STR + N_ROWS] = NNZ;
}

// ---------------------------------------------------------------------------
// 3a) Pass A: bucket scatter. LDS histogram + block-granular global
//     reservation (98 atomics/block) + LDS reorder -> coalesced runs.
//     Record: hi = (r_local<<17)|col, lo = val bits.
// ---------------------------------------------------------------------------
__global__ __launch_bounds__(256)
void fill_a(const int* __restrict__ rows, const int* __restrict__ cols,
            const float* __restrict__ vals, int* __restrict__ bcur,
            uint2* __restrict__ bkt)
{
    __shared__ int cnt[NBKT], lofs[NBKT], lcur[NBKT], gbase[NBKT];
    __shared__ uint2 stg[EPB_A];
    __shared__ int gpos[EPB_A];
    const int t  = threadIdx.x;
    const int e0 = blockIdx.x * EPB_A;
    const int n  = min(EPB_A, NNZ - e0);

    for (int b = t; b < NBKT; b += 256) cnt[b] = 0;
    __syncthreads();

    int rr[8], cc[8], bb[8]; unsigned vv[8];
    #pragma unroll
    for (int k = 0; k < 8; ++k) {
        const int idx = t + k * 256;
        if (idx < n) {
            const int e = e0 + idx;
            rr[k] = rows[e];
            cc[k] = cols[e];
            vv[k] = __float_as_uint(vals[e]);
            bb[k] = rr[k] >> 10;
            atomicAdd(&cnt[bb[k]], 1);
        } else bb[k] = -1;
    }
    __syncthreads();

    if (t == 0) {
        int run = 0;
        for (int b = 0; b < NBKT; ++b) { lofs[b] = run; run += cnt[b]; }
    }
    __syncthreads();
    if (t < NBKT) {
        gbase[t] = atomicAdd(&bcur[t], cnt[t]);
        lcur[t]  = lofs[t];
    }
    __syncthreads();

    #pragma unroll
    for (int k = 0; k < 8; ++k) {
        if (bb[k] >= 0) {
            const int p = atomicAdd(&lcur[bb[k]], 1);
            stg[p]  = make_uint2(((unsigned)(rr[k] & (RPB_F - 1)) << 17) |
                                 (unsigned)cc[k], vv[k]);
            gpos[p] = gbase[bb[k]] + (p - lofs[bb[k]]);
        }
    }
    __syncthreads();

    for (int p = t; p < n; p += 256)
        bkt[gpos[p]] = stg[p];
}

// ---------------------------------------------------------------------------
// 3b) Pass B: per-bucket fill with private LDS cursors. Coalesced reads,
//     scatter writes confined to an L2-resident ~130KB window.
// ---------------------------------------------------------------------------
__global__ __launch_bounds__(256)
void fill_b(const int* __restrict__ rs, const uint2* __restrict__ bkt,
            uint2* __restrict__ scv)
{
    __shared__ int cur[RPB_F];
    const int b  = blockIdx.x;
    const int r0 = b << 10;
    const int nr = min(RPB_F, N_ROWS - r0);
    const int t  = threadIdx.x;

    for (int i = t; i < nr; i += 256) cur[i] = rs[r0 + i];
    __syncthreads();

    const int e0 = rs[r0];
    const int e1 = rs[min(r0 + RPB_F, N_ROWS)];
    for (int e = e0 + t; e < e1; e += 256) {
        const uint2 rec = bkt[e];
        const int rl = (int)(rec.x >> 17);
        const int p  = atomicAdd(&cur[rl], 1);
        scv[p] = make_uint2(rec.x & 0x1FFFFu, rec.y);
    }
}

// ---------------------------------------------------------------------------
// 4a) Gather-SPMM vs LDS W (fp32): filtered[r] = bf16(sum v * W[c])
// ---------------------------------------------------------------------------
__global__ __launch_bounds__(256)
void gather_W(const int* __restrict__ rs, const uint2* __restrict__ scv,
              const float* __restrict__ W, __hip_bfloat16* __restrict__ dst)
{
    __shared__ float Wl[IN_C * OUT_C];
    for (int i = threadIdx.x; i < IN_C * OUT_C; i += blockDim.x) Wl[i] = W[i];
    __syncthreads();

    const int lane = threadIdx.x & 63;
    const int wave = blockIdx.x * 4 + (threadIdx.x >> 6);
    const int nw   = gridDim.x * 4;

    for (int r = wave; r < N_ROWS; r += nw) {
        const int s = rs[r], t = rs[r + 1];
        float a0 = 0.f, a1 = 0.f, a2 = 0.f, a3 = 0.f;
        int j = s;
        for (; j + 3 < t; j += 4) {
            const uint2 p0 = scv[j],     p1 = scv[j + 1];
            const uint2 p2 = scv[j + 2], p3 = scv[j + 3];
            a0 += __uint_as_float(p0.y) * Wl[p0.x * OUT_C + lane];
            a1 += __uint_as_float(p1.y) * Wl[p1.x * OUT_C + lane];
            a2 += __uint_as_float(p2.y) * Wl[p2.x * OUT_C + lane];
            a3 += __uint_as_float(p3.y) * Wl[p3.x * OUT_C + lane];
        }
        for (; j < t; ++j) {
            const uint2 p = scv[j];
            a0 += __uint_as_float(p.y) * Wl[p.x * OUT_C + lane];
        }
        dst[r * OUT_C + lane] = __float2bfloat16((a0 + a1) + (a2 + a3));
    }
}

// ---------------------------------------------------------------------------
// 4b) Gather-SPMM from bf16 src.
// MODE 1: dst[r] = bf16(theta[r] * sum v*src[c])
// MODE 2: out[(r*3+scale)] = relu(sum v*src[c])   (fp32)
// ---------------------------------------------------------------------------
template <int MODE>
__global__ __launch_bounds__(256)
void gather_mat(const int* __restrict__ rs, const uint2* __restrict__ scv,
                const __hip_bfloat16* __restrict__ src,
                const float* __restrict__ theta,
                __hip_bfloat16* __restrict__ dstb,
                float* __restrict__ dstf, int scale)
{
    const int lane = threadIdx.x & 63;
    const int wave = blockIdx.x * 4 + (threadIdx.x >> 6);
    const int nw   = gridDim.x * 4;

    for (int r = wave; r < N_ROWS; r += nw) {
        const int s = rs[r], t = rs[r + 1];
        float a0 = 0.f, a1 = 0.f, a2 = 0.f, a3 = 0.f;
        int j = s;
        for (; j + 3 < t; j += 4) {
            const uint2 p0 = scv[j],     p1 = scv[j + 1];
            const uint2 p2 = scv[j + 2], p3 = scv[j + 3];
            const float w0 = bf2f(src[p0.x * OUT_C + lane]);
            const float w1 = bf2f(src[p1.x * OUT_C + lane]);
            const float w2 = bf2f(src[p2.x * OUT_C + lane]);
            const float w3 = bf2f(src[p3.x * OUT_C + lane]);
            a0 += __uint_as_float(p0.y) * w0;
            a1 += __uint_as_float(p1.y) * w1;
            a2 += __uint_as_float(p2.y) * w2;
            a3 += __uint_as_float(p3.y) * w3;
        }
        for (; j < t; ++j) {
            const uint2 p = scv[j];
            a0 += __uint_as_float(p.y) * bf2f(src[p.x * OUT_C + lane]);
        }
        const float acc = (a0 + a1) + (a2 + a3);
        if (MODE == 1) {
            dstb[r * OUT_C + lane] = __float2bfloat16(theta[r] * acc);
        } else {
            dstf[(r * S_SC + scale) * OUT_C + lane] = acc > 0.0f ? acc : 0.0f;
        }
    }
}

extern "C" void kernel_launch(void* const* d_in, const int* in_sizes, int n_in,
                              void* d_out, int out_size, void* d_ws, size_t ws_size,
                              hipStream_t stream)
{
    const int*   phi_idx  = (const int*)d_in[0];
    const float* phi_val  = (const float*)d_in[1];
    const int*   pinv_idx = (const int*)d_in[2];
    const float* pinv_val = (const float*)d_in[3];
    const int*   fidx     = (const int*)d_in[4];
    const float* fval     = (const float*)d_in[5];
    const float* W        = (const float*)d_in[6];
    const float* theta    = (const float*)d_in[7];
    float*       out      = (float*)d_out;          // (N,S,64) fp32

    // ---- workspace (76.41 MB; 76.8 MB proven) ----
    __hip_bfloat16* filtered = (__hip_bfloat16*)d_ws;                  // 12.8 MB
    __hip_bfloat16* z        = filtered + (size_t)N_ROWS * OUT_C;      // 12.8 MB
    uint2* bkt = (uint2*)(z + (size_t)N_ROWS * OUT_C);                 // 12.8 MB
    uint2* scv = bkt + NNZ;                                            // 12.8 MB
    int*   counts8    = (int*)(scv + NNZ);                             // 22.4 MB
    int*   rs         = counts8 + (size_t)NMAT * NCOL * N_ROWS;        // 2.8 MB
    int*   bsum       = rs + (size_t)NMAT * RS_STR;                    // 7 KB
    int*   bucket_cur = bsum + NMAT * 256;                             // 2.7 KB

    // matrix order: 0=F, per scale i: 1+2i=PhiInv_i, 2+2i=Phi_i
    RowPtrs P;
    P.p[0] = fidx;
    for (int i = 0; i < S_SC; ++i) {
        P.p[1 + 2 * i] = pinv_idx + (size_t)(2 * i) * NNZ;
        P.p[2 + 2 * i] = phi_idx  + (size_t)(2 * i) * NNZ;
    }

    // ---- batched CSR metadata for all 7 matrices ----
    hist_binned<<<dim3(NCOL * NBIN_H, NMAT), 512, 0, stream>>>(P, counts8);
    scan_l1<<<dim3(BLKS_SCAN, NMAT), 256, 0, stream>>>(counts8, rs, bsum);
    scan_l2<<<NMAT, 256, 0, stream>>>(bsum);
    finalize<<<(NMAT * N_ROWS + 255) / 256, 256, 0, stream>>>(bsum, rs, bucket_cur);

    // ---- m=0: filtered = bf16(F @ W) ----
    fill_a<<<BLKS_A, 256, 0, stream>>>(fidx, fidx + NNZ, fval, bucket_cur, bkt);
    fill_b<<<NBKT, 256, 0, stream>>>(rs, bkt, scv);
    gather_W<<<2048, 256, 0, stream>>>(rs, scv, W, filtered);

    for (int i = 0; i < S_SC; ++i) {
        const int m1 = 1 + 2 * i, m2 = 2 + 2 * i;
        const int*   zc = pinv_idx + (size_t)(2 * i + 1) * NNZ;
        const float* zv = pinv_val + (size_t)i * NNZ;
        const int*   oc = phi_idx  + (size_t)(2 * i + 1) * NNZ;
        const float* ov = phi_val  + (size_t)i * NNZ;

        // z = bf16(theta ⊙ (PhiInv_i @ filtered))
        fill_a<<<BLKS_A, 256, 0, stream>>>(P.p[m1], zc, zv,
                                           bucket_cur + m1 * NBKT, bkt);
        fill_b<<<NBKT, 256, 0, stream>>>(rs + (size_t)m1 * RS_STR, bkt, scv);
        gather_mat<1><<<4096, 256, 0, stream>>>(rs + (size_t)m1 * RS_STR, scv,
                                                filtered, theta, z, nullptr, 0);

        // out[:, i, :] = relu(Phi_i @ z)
        fill_a<<<BLKS_A, 256, 0, stream>>>(P.p[m2], oc, ov,
                                           bucket_cur + m2 * NBKT, bkt);
        fill_b<<<NBKT, 256, 0, stream>>>(rs + (size_t)m2 * RS_STR, bkt, scv);
        gather_mat<2><<<4096, 256, 0, stream>>>(rs + (size_t)m2 * RS_STR, scv,
                                                z, nullptr, nullptr, out, i);
    }
}